// Round 19
// baseline (130.172 us; speedup 1.0000x reference)
//
#include <hip/hip_runtime.h>
#include <math.h>

#define BB 8
#define CC 64
#define NN 2048
#define KK 20
#define OO 128
#define CANDT 28
#define NPART 1024         // = k_knn grid (stats fused there)
#define NPARTB 1024        // Path-B standalone k_stats grid
#define M_TOT 327680.0f    // B*N*K

typedef __attribute__((ext_vector_type(8))) __bf16 bf8v;
typedef __attribute__((ext_vector_type(4))) float f32x4;

// ---------------------------------------------------------------------------
// k_pqprep (Path A): P/Q GEMMs + bf16 xT rows + f32 xTf rows + xx/xxf norms.
// ---------------------------------------------------------------------------
__global__ __launch_bounds__(256, 4) void k_pqprep(const float* __restrict__ x,
                                                   const float* __restrict__ W,
                                                   float* __restrict__ P,
                                                   float* __restrict__ Q,
                                                   ushort* __restrict__ xT,
                                                   float* __restrict__ xTf,
                                                   double* __restrict__ xx,
                                                   float* __restrict__ xxf) {
  __shared__ float xs[32][68];                     // 8.7 KB
  __shared__ float Wl[OO][68];                     // 34 KB
  __shared__ float tile[32][OO + 1];               // 16.5 KB
  const int t = threadIdx.x;
  const int jj = t & 31, og = t >> 5;              // 8 o-groups of 16
  const int pt0 = blockIdx.x * 32;
  const int b = pt0 >> 11;
  const int n0 = pt0 & (NN - 1);

#pragma unroll
  for (int r = 0; r < 2; ++r) {
    int seg = t + r * 256;
    int c = seg >> 3, n4 = (seg & 7) * 4;
    float4 v = *(const float4*)(x + ((size_t)(b * CC + c) << 11) + n0 + n4);
    xs[n4 + 0][c] = v.x; xs[n4 + 1][c] = v.y;
    xs[n4 + 2][c] = v.z; xs[n4 + 3][c] = v.w;
  }
#pragma unroll
  for (int r = 0; r < 8; ++r) {
    int seg = t + r * 256;                         // seg = o*16 + c4
    int o = seg >> 4, c4 = (seg & 15) * 4;
    *(float4*)(&Wl[o][c4]) = *(const float4*)(W + (size_t)o * (2 * CC) + c4);
  }
  __syncthreads();

  float xcol[CC];
#pragma unroll
  for (int c = 0; c < CC; c += 4) {
    float4 v = *(const float4*)(&xs[jj][c]);
    xcol[c] = v.x; xcol[c + 1] = v.y; xcol[c + 2] = v.z; xcol[c + 3] = v.w;
  }

  if (t < 32) {                                    // prep outputs (1 pt/thread)
    int i = pt0 + t;
    ushort* rowp = xT + (size_t)i * CC;
    float* rowf = xTf + (size_t)i * CC;
    double s = 0.0;
#pragma unroll
    for (int c8 = 0; c8 < 8; ++c8) {
      unsigned tmp[8];
      float f[8];
#pragma unroll
      for (int e = 0; e < 8; ++e) {
        float v = xs[t][c8 * 8 + e];
        f[e] = v;
        double dv = (double)v; s = fma(dv, dv, s);
        __bf16 h = (__bf16)v;
        ushort us; __builtin_memcpy(&us, &h, 2);
        tmp[e] = us;
      }
      uint4 pk;
      pk.x = tmp[0] | (tmp[1] << 16);
      pk.y = tmp[2] | (tmp[3] << 16);
      pk.z = tmp[4] | (tmp[5] << 16);
      pk.w = tmp[6] | (tmp[7] << 16);
      *(uint4*)(rowp + c8 * 8) = pk;
      *(float4*)(rowf + c8 * 8)     = make_float4(f[0], f[1], f[2], f[3]);
      *(float4*)(rowf + c8 * 8 + 4) = make_float4(f[4], f[5], f[6], f[7]);
    }
    xx[i] = s;
    xxf[i] = (float)s;
  }

  for (int oo = 0; oo < 16; ++oo) {
    int o = og * 16 + oo;
    float sp = 0.f;
#pragma unroll
    for (int c = 0; c < CC; c += 4) {
      float4 wv = *(const float4*)(&Wl[o][c]);
      sp = fmaf(wv.x, xcol[c], sp);
      sp = fmaf(wv.y, xcol[c + 1], sp);
      sp = fmaf(wv.z, xcol[c + 2], sp);
      sp = fmaf(wv.w, xcol[c + 3], sp);
    }
    tile[jj][o] = sp;
  }
  __syncthreads();
  for (int it = 0; it < 16; ++it) {
    int r = it * 2 + (t >> 7);
    P[((size_t)(pt0 + r)) * OO + (t & 127)] = tile[r][t & 127];
  }
#pragma unroll
  for (int r = 0; r < 8; ++r) {
    int seg = t + r * 256;
    int o = seg >> 4, c4 = (seg & 15) * 4;
    const float* wr = W + (size_t)o * (2 * CC);
    float4 w1 = *(const float4*)(wr + c4);
    float4 w2 = *(const float4*)(wr + CC + c4);
    float4 wd = make_float4(w2.x - w1.x, w2.y - w1.y, w2.z - w1.z, w2.w - w1.w);
    *(float4*)(&Wl[o][c4]) = wd;
  }
  __syncthreads();
  for (int oo = 0; oo < 16; ++oo) {
    int o = og * 16 + oo;
    float sq = 0.f;
#pragma unroll
    for (int c = 0; c < CC; c += 4) {
      float4 wv = *(const float4*)(&Wl[o][c]);
      sq = fmaf(wv.x, xcol[c], sq);
      sq = fmaf(wv.y, xcol[c + 1], sq);
      sq = fmaf(wv.z, xcol[c + 2], sq);
      sq = fmaf(wv.w, xcol[c + 3], sq);
    }
    tile[jj][o] = sq;
  }
  __syncthreads();
  for (int it = 0; it < 16; ++it) {
    int r = it * 2 + (t >> 7);
    Q[((size_t)(pt0 + r)) * OO + (t & 127)] = tile[r][t & 127];
  }
}

// ---------------------------------------------------------------------------
// k_prep (Path B fallback): standalone prep pass.
// ---------------------------------------------------------------------------
__global__ __launch_bounds__(256) void k_prep(const float* __restrict__ x,
                                              ushort* __restrict__ xT,
                                              float* __restrict__ xTf,
                                              double* __restrict__ xx,
                                              float* __restrict__ xxf) {
  int i = blockIdx.x * 256 + threadIdx.x;
  int b = i >> 11, n = i & (NN - 1);
  const float* p = x + ((size_t)b * CC) * NN + n;
  ushort* rowp = xT + (size_t)i * CC;
  float* rowf = xTf + (size_t)i * CC;
  double s = 0.0;
#pragma unroll
  for (int c8 = 0; c8 < 8; ++c8) {
    float f[8];
    unsigned tmp[8];
#pragma unroll
    for (int e = 0; e < 8; ++e) {
      float v = p[(size_t)(c8 * 8 + e) * NN];
      f[e] = v;
      double dv = (double)v; s = fma(dv, dv, s);
      __bf16 h = (__bf16)v;
      ushort us; __builtin_memcpy(&us, &h, 2);
      tmp[e] = us;
    }
    uint4 pk;
    pk.x = tmp[0] | (tmp[1] << 16);
    pk.y = tmp[2] | (tmp[3] << 16);
    pk.z = tmp[4] | (tmp[5] << 16);
    pk.w = tmp[6] | (tmp[7] << 16);
    *(uint4*)(rowp + c8 * 8) = pk;
    *(float4*)(rowf + c8 * 8)     = make_float4(f[0], f[1], f[2], f[3]);
    *(float4*)(rowf + c8 * 8 + 4) = make_float4(f[4], f[5], f[6], f[7]);
  }
  xx[i] = s;
  xxf[i] = (float)s;
}

// ---------------------------------------------------------------------------
// k_pq (Path B fallback): P/Q GEMMs only.
// ---------------------------------------------------------------------------
__global__ __launch_bounds__(256) void k_pq(const float* __restrict__ x,
                                            const float* __restrict__ W,
                                            float* __restrict__ P,
                                            float* __restrict__ Q) {
  __shared__ float tile[64][OO + 1];
  const int t = threadIdx.x;
  const int jj = t & 63, og = t >> 6;
  const int pt0 = blockIdx.x * 64;
  const int b = pt0 >> 11;
  const int jn = (pt0 & (NN - 1)) + jj;

  float xcol[CC];
#pragma unroll
  for (int c = 0; c < CC; ++c) xcol[c] = x[((size_t)(b * CC + c) << 11) + jn];

  for (int oo = 0; oo < 32; ++oo) {
    int o = og * 32 + oo;
    const float* wr = W + (size_t)o * (2 * CC);
    float sp = 0.f;
#pragma unroll
    for (int c = 0; c < CC; ++c) sp = fmaf(wr[c], xcol[c], sp);
    tile[jj][o] = sp;
  }
  __syncthreads();
  for (int it = 0; it < 32; ++it) {
    int r = it * 2 + (t >> 7);
    P[((size_t)(pt0 + r)) * OO + (t & 127)] = tile[r][t & 127];
  }
  __syncthreads();
  for (int oo = 0; oo < 32; ++oo) {
    int o = og * 32 + oo;
    const float* wr = W + (size_t)o * (2 * CC);
    float sq = 0.f;
#pragma unroll
    for (int c = 0; c < CC; ++c) sq = fmaf(wr[CC + c] - wr[c], xcol[c], sq);
    tile[jj][o] = sq;
  }
  __syncthreads();
  for (int it = 0; it < 32; ++it) {
    int r = it * 2 + (t >> 7);
    Q[((size_t)(pt0 + r)) * OO + (t & 127)] = tile[r][t & 127];
  }
}

// ---------------------------------------------------------------------------
// k_knn (R19): 16-row tiles, 1024 blocks x 1024 thr, 77.3KB LDS -> 2 blocks/
// CU = 8 waves/SIMD (R18 was 1 block, 4 waves/SIMD, VALUBusy 48% latency-
// bound). Phase A: mfma 16x16x32 (m89 C/D map), split halves (16 AGPRs live,
// A-frags 8 VGPRs). Phase C: ONE row per wave, R18 pipeline (b128 keys,
// reg masks, CANDT 28). fp64 rescore order identical -> same output.
// ---------------------------------------------------------------------------
__device__ __forceinline__ void exact_radix_q(const uint4* kq, int lane,
                                              unsigned& tau, unsigned& mask,
                                              int& myc, int& pre, int& tot) {
  tau = 0;
  for (int bit = 15; bit >= 0; --bit) {
    unsigned cnd = tau | (1u << bit);
    int cc = 0;
#pragma unroll
    for (int g = 0; g < 4; ++g) {
      const unsigned wds[4] = {kq[g].x, kq[g].y, kq[g].z, kq[g].w};
#pragma unroll
      for (int e = 0; e < 4; ++e) {
        cc += ((wds[e] & 0xffffu) >= cnd) ? 1 : 0;
        cc += ((wds[e] >> 16) >= cnd) ? 1 : 0;
      }
    }
#pragma unroll
    for (int off = 1; off < 64; off <<= 1) cc += __shfl_xor(cc, off, 64);
    if (cc >= CANDT) tau = cnd;
  }
  mask = 0;
#pragma unroll
  for (int g = 0; g < 4; ++g) {
    const unsigned wds[4] = {kq[g].x, kq[g].y, kq[g].z, kq[g].w};
#pragma unroll
    for (int e = 0; e < 4; ++e) {
      mask |= ((wds[e] & 0xffffu) >= tau ? 1u : 0u) << (g * 8 + e * 2);
      mask |= ((wds[e] >> 16) >= tau ? 1u : 0u) << (g * 8 + e * 2 + 1);
    }
  }
  myc = __popc(mask); pre = myc;
#pragma unroll
  for (int off = 1; off < 64; off <<= 1) {
    int o = __shfl_up(pre, off, 64);
    pre += (lane >= off) ? o : 0;
  }
  tot = __shfl(pre, 63, 64);
}

__global__ __launch_bounds__(1024, 8) void k_knn(
    const ushort* __restrict__ xT, const float* __restrict__ xxf,
    const float* __restrict__ xTf, const double* __restrict__ xx,
    int* __restrict__ idx, const float* __restrict__ P,
    const float* __restrict__ Q, float* __restrict__ partial,
    float* __restrict__ vmaxA, float* __restrict__ vminA) {
  extern __shared__ char smem[];
  ushort (*Sb)[NN] = (ushort(*)[NN])smem;          // [16][2048] u16 keys 64KB
  int (*CjS)[64] = (int(*)[64])(smem + 16 * NN * 2);           // [16][64] 4KB
  double (*SdS)[64] = (double(*)[64])(smem + 16 * NN * 2 + 4096); // [16][64] 8KB
  float* redF = (float*)SdS;                       // reuse as [2][8][128] in D
  int (*sIdxL)[KK] = (int(*)[KK])(smem + 16 * NN * 2 + 4096 + 8192); // 1.25KB
  const int t = threadIdx.x;
  const int w = t >> 6, lane = t & 63;
  const int bidswz = ((blockIdx.x & 7) << 7) + (blockIdx.x >> 3); // batch/XCD
  const int b = bidswz >> 7;
  const int i0 = (bidswz & 127) << 4;
  const int lr16 = lane & 15, kg = lane >> 4;
  const ushort* xTb = xT + (((size_t)b) << 11) * CC;
  const float* xxfb = xxf + (b << 11);

  // ---- Phase A+B: 16x16x32 MFMA in 2 halves (16 AGPRs live) ----
  const ushort* Arow = xTb + (size_t)(i0 + lr16) * CC + kg * 8;
  bf8v aF0 = *(const bf8v*)(Arow);
  bf8v aF1 = *(const bf8v*)(Arow + 32);
  const int j0w = w << 7;
#pragma unroll 1
  for (int h = 0; h < 2; ++h) {
    f32x4 acc4[4];
#pragma unroll
    for (int u = 0; u < 4; ++u)
#pragma unroll
      for (int q = 0; q < 4; ++q) acc4[u][q] = 0.f;
#pragma unroll
    for (int u = 0; u < 4; ++u) {
      const int ct = h * 4 + u;
      const ushort* Brow = xTb + (size_t)(j0w + ct * 16 + lr16) * CC + kg * 8;
      bf8v bF0 = *(const bf8v*)(Brow);
      bf8v bF1 = *(const bf8v*)(Brow + 32);
      acc4[u] = __builtin_amdgcn_mfma_f32_16x16x32_bf16(aF0, bF0, acc4[u], 0, 0, 0);
      acc4[u] = __builtin_amdgcn_mfma_f32_16x16x32_bf16(aF1, bF1, acc4[u], 0, 0, 0);
    }
#pragma unroll
    for (int u = 0; u < 4; ++u) {
      const int ct = h * 4 + u;
      int j = j0w + ct * 16 + lr16;
      float xv = xxfb[j];
#pragma unroll
      for (int q = 0; q < 4; ++q) {
        int rr = kg * 4 + q;                       // 16x16 C/D map (m89)
        float sv = fmaf(2.f, acc4[u][q], -xv);
        unsigned uu = __float_as_uint(sv);
        uu ^= (0x80000000u | (unsigned)((int)uu >> 31)); // monotone u32
        Sb[rr][j] = (ushort)(uu >> 16);
      }
    }
  }
  __syncthreads();

  // ---- Phase C: wave w owns row w (single row; 8 waves/SIMD hide stalls) ----
  const float* xTfb = xTf + (((size_t)b) << 11) * CC;
  const double* xxb = xx + (b << 11);
  const int rr = w;
  const int irow = i0 + rr;

  uint4 kq[4];
  unsigned t0 = 0, t1 = 0, t2 = 0, t3 = 0;
#pragma unroll
  for (int g = 0; g < 4; ++g) {
    uint4 raw = *(const uint4*)(&Sb[rr][lane * 8 + g * 512]);
    kq[g] = raw;
    const unsigned wds[4] = {raw.x, raw.y, raw.z, raw.w};
#pragma unroll
    for (int e = 0; e < 4; ++e) {
      unsigned k0 = wds[e] & 0xffffu, k1 = wds[e] >> 16;
      unsigned mx, mn;
      mx = k0 > t0 ? k0 : t0; mn = k0 > t0 ? t0 : k0; t0 = mx;
      mx = mn > t1 ? mn : t1; mn = mn > t1 ? t1 : mn; t1 = mx;
      mx = mn > t2 ? mn : t2; mn = mn > t2 ? t2 : mn; t2 = mx;
      t3 = mn > t3 ? mn : t3;
      mx = k1 > t0 ? k1 : t0; mn = k1 > t0 ? t0 : k1; t0 = mx;
      mx = mn > t1 ? mn : t1; mn = mn > t1 ? t1 : mn; t1 = mx;
      mx = mn > t2 ? mn : t2; mn = mn > t2 ? t2 : mn; t2 = mx;
      t3 = mn > t3 ? mn : t3;
    }
  }
  unsigned tau = 0;
  for (int bit = 15; bit >= 0; --bit) {
    unsigned cnd = tau | (1u << bit);
    int tot_ = __popcll(__ballot(t0 >= cnd)) + __popcll(__ballot(t1 >= cnd)) +
               __popcll(__ballot(t2 >= cnd)) + __popcll(__ballot(t3 >= cnd));
    if (tot_ >= CANDT) tau = cnd;
  }
  unsigned mask = 0;
#pragma unroll
  for (int g = 0; g < 4; ++g) {
    const unsigned wds[4] = {kq[g].x, kq[g].y, kq[g].z, kq[g].w};
#pragma unroll
    for (int e = 0; e < 4; ++e) {
      mask |= ((wds[e] & 0xffffu) >= tau ? 1u : 0u) << (g * 8 + e * 2);
      mask |= ((wds[e] >> 16) >= tau ? 1u : 0u) << (g * 8 + e * 2 + 1);
    }
  }
  int myc = __popc(mask);
  int pre = myc;
#pragma unroll
  for (int off = 1; off < 64; off <<= 1) {
    int o = __shfl_up(pre, off, 64);
    pre += (lane >= off) ? o : 0;
  }
  int tot = __shfl(pre, 63, 64);
  if (tot > 64) exact_radix_q(kq, lane, tau, mask, myc, pre, tot); // cold
  {
    int slot = pre - myc;
    unsigned m2 = mask;
    while (m2) {
      int bp = __builtin_ctz(m2); m2 &= m2 - 1;
      if (slot < 64) CjS[rr][slot] = lane * 8 + ((bp >> 3) << 9) + (bp & 7);
      ++slot;
    }
  }
  const int cnt = tot > 64 ? 64 : tot;
  int j = CjS[rr][lane < cnt ? lane : 0];
  const float* xi = xTfb + (size_t)irow * CC;
  const float* xj = xTfb + (size_t)j * CC;
  double d0 = 0, d1 = 0, d2 = 0, d3 = 0;
#pragma unroll
  for (int c = 0; c < CC; c += 4) {
    float4 fi = *(const float4*)(xi + c);
    float4 fj = *(const float4*)(xj + c);
    d0 = fma((double)fi.x, (double)fj.x, d0);
    d1 = fma((double)fi.y, (double)fj.y, d1);
    d2 = fma((double)fi.z, (double)fj.z, d2);
    d3 = fma((double)fi.w, (double)fj.w, d3);
  }
  double sc = 2.0 * ((d0 + d1) + (d2 + d3)) - xxb[j];
  SdS[rr][lane] = sc;
  int rank = 0;
#pragma unroll 4
  for (int mm = 0; mm < cnt; ++mm) {
    double sm = SdS[rr][mm];
    int jm = CjS[rr][mm];
    rank += (sm > sc || (sm == sc && jm < j)) ? 1 : 0;
  }
  if (lane < cnt && rank < KK) {
    idx[(size_t)((b << 11) + irow) * KK + rank] = j;
    sIdxL[rr][rank] = j;
  }

  // ---- Phase D: fused gather-stats (skipped when P==nullptr, Path B) ----
  if (P != nullptr) {
    __syncthreads();                               // sIdxL complete; SdS free
    const int grp = t >> 7;                        // 0..7 (2 points each)
    const int o = t & 127;
    float s = 0.f, s2 = 0.f;
#pragma unroll
    for (int pp = 0; pp < 2; ++pp) {
      const int pl = grp * 2 + pp;                 // local row 0..15
      const int pt = (b << 11) + i0 + pl;          // global point
      float qv = Q[(size_t)pt * OO + o];
      float vmax = -3.0e38f, vmin = 3.0e38f;
#pragma unroll
      for (int k = 0; k < KK; ++k) {
        float v = P[((size_t)((b << 11) + sIdxL[pl][k])) * OO + o] + qv;
        s += v;
        s2 = fmaf(v, v, s2);
        vmax = fmaxf(vmax, v);
        vmin = fminf(vmin, v);
      }
      vmaxA[(size_t)pt * OO + o] = vmax;
      vminA[(size_t)pt * OO + o] = vmin;
    }
    redF[grp * 128 + o] = s;
    redF[1024 + grp * 128 + o] = s2;
    __syncthreads();
    if (t < 128) {
      float as = 0.f, as2 = 0.f;
#pragma unroll
      for (int g = 0; g < 8; ++g) {                // fixed order: deterministic
        as  += redF[g * 128 + t];
        as2 += redF[1024 + g * 128 + t];
      }
      partial[(size_t)bidswz * 128 + t]               = as;
      partial[(size_t)NPART * 128 + (size_t)bidswz * 128 + t] = as2;
    }
  }
}

// ---------------------------------------------------------------------------
// k_stats (Path B fallback): standalone gather-stats.
// ---------------------------------------------------------------------------
__global__ __launch_bounds__(256) void k_stats(const float* __restrict__ P,
                                               const float* __restrict__ Q,
                                               const int* __restrict__ idx,
                                               float* __restrict__ partial) {
  __shared__ int sIdx[16 * KK];
  __shared__ float red[512];
  const int t = threadIdx.x;
  const int o = t & 127, half = t >> 7;
  const int bid = (blockIdx.x & 7) * 128 + (blockIdx.x >> 3);
  const int pt0 = bid * 16;
  const int b = pt0 >> 11;
  if (t < 160)
    *(int2*)(sIdx + t * 2) = *(const int2*)(idx + (size_t)pt0 * KK + t * 2);
  __syncthreads();

  float s = 0.f, s2 = 0.f;
  for (int it = 0; it < 8; ++it) {
    int pl = it * 2 + half;
    int pt = pt0 + pl;
    float qv = Q[(size_t)pt * OO + o];
    const int* ip = sIdx + pl * KK;
#pragma unroll
    for (int k = 0; k < KK; ++k) {
      float v = P[((size_t)((b << 11) + ip[k])) * OO + o] + qv;
      s += v;
      s2 = fmaf(v, v, s2);
    }
  }
  red[t] = s; red[256 + t] = s2;
  __syncthreads();
  if (t < 128) {
    partial[bid * 128 + o]                = red[t] + red[t + 128];
    partial[NPARTB * 128 + bid * 128 + o] = red[256 + t] + red[256 + t + 128];
  }
}

// ---------------------------------------------------------------------------
// k_fin: single-kernel BN finalize. 128 blocks (one per o); npart variable.
// ---------------------------------------------------------------------------
__global__ __launch_bounds__(256) void k_fin(const float* __restrict__ partial,
                                             const float* __restrict__ gamma,
                                             const float* __restrict__ beta,
                                             float* __restrict__ ss, int npart) {
  __shared__ float red[2][256];
  const int o = blockIdx.x;
  const int t = threadIdx.x;
  float s = 0.f, s2 = 0.f;
  for (int blk = t; blk < npart; blk += 256) {
    s  += partial[(size_t)blk * 128 + o];
    s2 += partial[(size_t)npart * 128 + (size_t)blk * 128 + o];
  }
  red[0][t] = s; red[1][t] = s2;
  __syncthreads();
  for (int st = 128; st >= 1; st >>= 1) {
    if (t < st) { red[0][t] += red[0][t + st]; red[1][t] += red[1][t + st]; }
    __syncthreads();
  }
  if (t == 0) {
    float mean = red[0][0] * (1.0f / M_TOT);
    float var  = red[1][0] * (1.0f / M_TOT) - mean * mean;
    float rs = 1.0f / sqrtf(var + 1e-5f);
    float scale = gamma[o] * rs;
    ss[o] = scale;
    ss[128 + o] = beta[o] - mean * scale;
  }
}

// ---------------------------------------------------------------------------
// k_out: BN affine -> exact GELU -> max over k -> out[b][o][n].
// ---------------------------------------------------------------------------
__global__ __launch_bounds__(256, 8) void k_out(const float* __restrict__ P,
                                                const float* __restrict__ Q,
                                                const int* __restrict__ idx,
                                                const float* __restrict__ ss,
                                                const float* __restrict__ vmaxA,
                                                const float* __restrict__ vminA,
                                                int use_minmax,
                                                float* __restrict__ out) {
  __shared__ float tile[32][OO + 1];               // 16.5 KB
  const int t = threadIdx.x;
  const int o = t & 127, half = t >> 7;
  const int bid = (blockIdx.x & 7) * 64 + (blockIdx.x >> 3);   // batch/XCD
  const float scale = ss[o], shift = ss[128 + o];
  const int pt0 = bid * 32;
  const int b = pt0 >> 11;
  const float inv_sqrt2 = 0.70710678118654752f;
  for (int it = 0; it < 16; ++it) {
    int pl = it * 2 + half;
    int pt = pt0 + pl;
    float vmax, vmin;
    if (use_minmax) {
      vmax = vmaxA[(size_t)pt * OO + o];
      vmin = vminA[(size_t)pt * OO + o];
    } else {
      float qv = Q[(size_t)pt * OO + o];
      const int* ip = idx + (size_t)pt * KK;
      vmax = -3.0e38f; vmin = 3.0e38f;
#pragma unroll
      for (int k = 0; k < KK; ++k) {
        float v = P[((size_t)((b << 11) + ip[k])) * OO + o] + qv;
        vmax = fmaxf(vmax, v);
        vmin = fminf(vmin, v);
      }
    }
    float ymax, ymin;
    if (scale >= 0.f) { ymax = fmaf(vmax, scale, shift); ymin = fmaf(vmin, scale, shift); }
    else              { ymax = fmaf(vmin, scale, shift); ymin = fmaf(vmax, scale, shift); }
    float g;
    if (ymax > 0.f) {
      g = 0.5f * ymax * (1.0f + erff(ymax * inv_sqrt2));
    } else {
      float g1 = 0.5f * ymax * (1.0f + erff(ymax * inv_sqrt2));
      float g2 = 0.5f * ymin * (1.0f + erff(ymin * inv_sqrt2));
      g = fmaxf(g1, g2);
    }
    tile[pl][o] = g;
  }
  __syncthreads();
  const int n0 = pt0 & (NN - 1);
  for (int rep = 0; rep < 16; ++rep) {
    int oo = rep * 8 + (t >> 5);
    int nn = t & 31;
    out[((size_t)(b * OO + oo) << 11) + n0 + nn] = tile[nn][oo];
  }
}

// ---------------------------------------------------------------------------
extern "C" void kernel_launch(void* const* d_in, const int* in_sizes, int n_in,
                              void* d_out, int out_size, void* d_ws, size_t ws_size,
                              hipStream_t stream) {
  const float* x     = (const float*)d_in[0];
  const float* W     = (const float*)d_in[1];
  const float* gamma = (const float*)d_in[2];
  const float* beta  = (const float*)d_in[3];
  float* out = (float*)d_out;

  const int knn_lds = 16 * NN * 2 + 4096 + 8192 + 16 * KK * 4;  // 79104 B
  hipFuncSetAttribute((const void*)k_knn,
                      hipFuncAttributeMaxDynamicSharedMemorySize, knn_lds);

  const size_t needA = 131072 + 65536 + 1310720 + (size_t)2 * NPARTB * 128 * 4 +
                       1024 + 4ull * 8388608;

  if (ws_size >= needA) {
    // Path A layout
    double* xx   = (double*)d_ws;                      // 131072 B
    float*  xxf  = (float*)(xx + BB * NN);             // 65536 B
    int*    idxp = (int*)(xxf + BB * NN);              // 1310720 B
    float*  part = (float*)(idxp + (size_t)BB * NN * KK); // 1 MB
    float*  ss   = part + 2 * NPARTB * 128;            // 1024 B
    float*  P    = ss + 256;                           // 8 MB
    float*  Q    = P + (size_t)BB * NN * OO;           // 8 MB
    ushort* xT   = (ushort*)(Q + (size_t)BB * NN * OO);// 2 MB
    float*  xTf  = (float*)(xT + (size_t)BB * NN * CC);// 4 MB
    float*  vmax = xTf + (size_t)BB * NN * CC;         // 8 MB (no alias: knn-D)
    float*  vmin = vmax + (size_t)BB * NN * OO;        // 8 MB
    const size_t needSafe = (size_t)((char*)(vmin + (size_t)BB * NN * OO) - (char*)d_ws);
    if (ws_size >= needSafe) {
      hipLaunchKernelGGL(k_pqprep, dim3(BB * NN / 32), dim3(256), 0, stream,
                         x, W, P, Q, xT, xTf, xx, xxf);
      hipLaunchKernelGGL(k_knn, dim3(BB * NN / 16), dim3(1024), knn_lds, stream,
                         xT, xxf, xTf, xx, idxp, P, Q, part, vmax, vmin);
      hipLaunchKernelGGL(k_fin, dim3(128), dim3(256), 0, stream, part, gamma, beta, ss, NPART);
      hipLaunchKernelGGL(k_out, dim3(BB * NN / 32), dim3(256), 0, stream,
                         P, Q, idxp, ss, vmax, vmin, 1, out);
      return;
    }
    // ws too small for safe vmax/vmin: alias xT/xTf region, no fused stats
    ushort* xTa  = (ushort*)(Q + (size_t)BB * NN * OO);
    float*  xTfa = (float*)(xTa + (size_t)BB * NN * CC);
    hipLaunchKernelGGL(k_pqprep, dim3(BB * NN / 32), dim3(256), 0, stream,
                       x, W, P, Q, xTa, xTfa, xx, xxf);
    hipLaunchKernelGGL(k_knn, dim3(BB * NN / 16), dim3(1024), knn_lds, stream,
                       xTa, xxf, xTfa, xx, idxp,
                       (const float*)nullptr, (const float*)nullptr,
                       (float*)nullptr, (float*)nullptr, (float*)nullptr);
    hipLaunchKernelGGL(k_stats, dim3(NPARTB), dim3(256), 0, stream,
                       P, Q, idxp, part);
    hipLaunchKernelGGL(k_fin, dim3(128), dim3(256), 0, stream, part, gamma, beta, ss, NPARTB);
    hipLaunchKernelGGL(k_out, dim3(BB * NN / 32), dim3(256), 0, stream,
                       P, Q, idxp, ss, (const float*)nullptr, (const float*)nullptr, 0, out);
  } else {
    // Path B layout (minimal ws)
    double* xx   = (double*)d_ws;
    int*    idxp = (int*)(xx + BB * NN);
    float*  P    = (float*)(idxp + (size_t)BB * NN * KK);
    float*  Q    = P + (size_t)BB * NN * OO;
    float*  part = Q + (size_t)BB * NN * OO;
    float*  ss   = part + 2 * NPARTB * 128;
    ushort* xT   = (ushort*)P;
    float*  xTf  = P + (size_t)BB * NN * (CC / 2);
    float*  xxf  = Q;

    hipLaunchKernelGGL(k_prep, dim3(BB * NN / 256), dim3(256), 0, stream,
                       x, xT, xTf, xx, xxf);
    hipLaunchKernelGGL(k_knn, dim3(BB * NN / 16), dim3(1024), knn_lds, stream,
                       xT, xxf, xTf, xx, idxp,
                       (const float*)nullptr, (const float*)nullptr,
                       (float*)nullptr, (float*)nullptr, (float*)nullptr);
    hipLaunchKernelGGL(k_pq, dim3(BB * NN / 64), dim3(256), 0, stream, x, W, P, Q);
    hipLaunchKernelGGL(k_stats, dim3(NPARTB), dim3(256), 0, stream,
                       P, Q, idxp, part);
    hipLaunchKernelGGL(k_fin, dim3(128), dim3(256), 0, stream, part, gamma, beta, ss, NPARTB);
    hipLaunchKernelGGL(k_out, dim3(BB * NN / 32), dim3(256), 0, stream,
                       P, Q, idxp, ss, (const float*)nullptr, (const float*)nullptr, 0, out);
  }
}

// Round 20
// 110.358 us; speedup vs baseline: 1.1795x; 1.1795x over previous
//
#include <hip/hip_runtime.h>
#include <math.h>

#define BB 8
#define CC 64
#define NN 2048
#define KK 20
#define OO 128
#define CANDT 28
#define NPART 512          // = k_knn grid (stats fused there)
#define NPARTB 1024        // Path-B standalone k_stats grid
#define M_TOT 327680.0f    // B*N*K

typedef __attribute__((ext_vector_type(8))) __bf16 bf8v;
typedef __attribute__((ext_vector_type(16))) float f32x16;

// ---------------------------------------------------------------------------
// k_pqprep (Path A): P/Q GEMMs + bf16 xT rows + f32 xTf rows + xx/xxf norms.
// ---------------------------------------------------------------------------
__global__ __launch_bounds__(256, 4) void k_pqprep(const float* __restrict__ x,
                                                   const float* __restrict__ W,
                                                   float* __restrict__ P,
                                                   float* __restrict__ Q,
                                                   ushort* __restrict__ xT,
                                                   float* __restrict__ xTf,
                                                   double* __restrict__ xx,
                                                   float* __restrict__ xxf) {
  __shared__ float xs[32][68];                     // 8.7 KB
  __shared__ float Wl[OO][68];                     // 34 KB
  __shared__ float tile[32][OO + 1];               // 16.5 KB
  const int t = threadIdx.x;
  const int jj = t & 31, og = t >> 5;              // 8 o-groups of 16
  const int pt0 = blockIdx.x * 32;
  const int b = pt0 >> 11;
  const int n0 = pt0 & (NN - 1);

#pragma unroll
  for (int r = 0; r < 2; ++r) {
    int seg = t + r * 256;
    int c = seg >> 3, n4 = (seg & 7) * 4;
    float4 v = *(const float4*)(x + ((size_t)(b * CC + c) << 11) + n0 + n4);
    xs[n4 + 0][c] = v.x; xs[n4 + 1][c] = v.y;
    xs[n4 + 2][c] = v.z; xs[n4 + 3][c] = v.w;
  }
#pragma unroll
  for (int r = 0; r < 8; ++r) {
    int seg = t + r * 256;                         // seg = o*16 + c4
    int o = seg >> 4, c4 = (seg & 15) * 4;
    *(float4*)(&Wl[o][c4]) = *(const float4*)(W + (size_t)o * (2 * CC) + c4);
  }
  __syncthreads();

  float xcol[CC];
#pragma unroll
  for (int c = 0; c < CC; c += 4) {
    float4 v = *(const float4*)(&xs[jj][c]);
    xcol[c] = v.x; xcol[c + 1] = v.y; xcol[c + 2] = v.z; xcol[c + 3] = v.w;
  }

  if (t < 32) {                                    // prep outputs (1 pt/thread)
    int i = pt0 + t;
    ushort* rowp = xT + (size_t)i * CC;
    float* rowf = xTf + (size_t)i * CC;
    double s = 0.0;
#pragma unroll
    for (int c8 = 0; c8 < 8; ++c8) {
      unsigned tmp[8];
      float f[8];
#pragma unroll
      for (int e = 0; e < 8; ++e) {
        float v = xs[t][c8 * 8 + e];
        f[e] = v;
        double dv = (double)v; s = fma(dv, dv, s);
        __bf16 h = (__bf16)v;
        ushort us; __builtin_memcpy(&us, &h, 2);
        tmp[e] = us;
      }
      uint4 pk;
      pk.x = tmp[0] | (tmp[1] << 16);
      pk.y = tmp[2] | (tmp[3] << 16);
      pk.z = tmp[4] | (tmp[5] << 16);
      pk.w = tmp[6] | (tmp[7] << 16);
      *(uint4*)(rowp + c8 * 8) = pk;
      *(float4*)(rowf + c8 * 8)     = make_float4(f[0], f[1], f[2], f[3]);
      *(float4*)(rowf + c8 * 8 + 4) = make_float4(f[4], f[5], f[6], f[7]);
    }
    xx[i] = s;
    xxf[i] = (float)s;
  }

  for (int oo = 0; oo < 16; ++oo) {
    int o = og * 16 + oo;
    float sp = 0.f;
#pragma unroll
    for (int c = 0; c < CC; c += 4) {
      float4 wv = *(const float4*)(&Wl[o][c]);
      sp = fmaf(wv.x, xcol[c], sp);
      sp = fmaf(wv.y, xcol[c + 1], sp);
      sp = fmaf(wv.z, xcol[c + 2], sp);
      sp = fmaf(wv.w, xcol[c + 3], sp);
    }
    tile[jj][o] = sp;
  }
  __syncthreads();
  for (int it = 0; it < 16; ++it) {
    int r = it * 2 + (t >> 7);
    P[((size_t)(pt0 + r)) * OO + (t & 127)] = tile[r][t & 127];
  }
#pragma unroll
  for (int r = 0; r < 8; ++r) {
    int seg = t + r * 256;
    int o = seg >> 4, c4 = (seg & 15) * 4;
    const float* wr = W + (size_t)o * (2 * CC);
    float4 w1 = *(const float4*)(wr + c4);
    float4 w2 = *(const float4*)(wr + CC + c4);
    float4 wd = make_float4(w2.x - w1.x, w2.y - w1.y, w2.z - w1.z, w2.w - w1.w);
    *(float4*)(&Wl[o][c4]) = wd;
  }
  __syncthreads();
  for (int oo = 0; oo < 16; ++oo) {
    int o = og * 16 + oo;
    float sq = 0.f;
#pragma unroll
    for (int c = 0; c < CC; c += 4) {
      float4 wv = *(const float4*)(&Wl[o][c]);
      sq = fmaf(wv.x, xcol[c], sq);
      sq = fmaf(wv.y, xcol[c + 1], sq);
      sq = fmaf(wv.z, xcol[c + 2], sq);
      sq = fmaf(wv.w, xcol[c + 3], sq);
    }
    tile[jj][o] = sq;
  }
  __syncthreads();
  for (int it = 0; it < 16; ++it) {
    int r = it * 2 + (t >> 7);
    Q[((size_t)(pt0 + r)) * OO + (t & 127)] = tile[r][t & 127];
  }
}

// ---------------------------------------------------------------------------
// k_prep (Path B fallback): standalone prep pass.
// ---------------------------------------------------------------------------
__global__ __launch_bounds__(256) void k_prep(const float* __restrict__ x,
                                              ushort* __restrict__ xT,
                                              float* __restrict__ xTf,
                                              double* __restrict__ xx,
                                              float* __restrict__ xxf) {
  int i = blockIdx.x * 256 + threadIdx.x;
  int b = i >> 11, n = i & (NN - 1);
  const float* p = x + ((size_t)b * CC) * NN + n;
  ushort* rowp = xT + (size_t)i * CC;
  float* rowf = xTf + (size_t)i * CC;
  double s = 0.0;
#pragma unroll
  for (int c8 = 0; c8 < 8; ++c8) {
    float f[8];
    unsigned tmp[8];
#pragma unroll
    for (int e = 0; e < 8; ++e) {
      float v = p[(size_t)(c8 * 8 + e) * NN];
      f[e] = v;
      double dv = (double)v; s = fma(dv, dv, s);
      __bf16 h = (__bf16)v;
      ushort us; __builtin_memcpy(&us, &h, 2);
      tmp[e] = us;
    }
    uint4 pk;
    pk.x = tmp[0] | (tmp[1] << 16);
    pk.y = tmp[2] | (tmp[3] << 16);
    pk.z = tmp[4] | (tmp[5] << 16);
    pk.w = tmp[6] | (tmp[7] << 16);
    *(uint4*)(rowp + c8 * 8) = pk;
    *(float4*)(rowf + c8 * 8)     = make_float4(f[0], f[1], f[2], f[3]);
    *(float4*)(rowf + c8 * 8 + 4) = make_float4(f[4], f[5], f[6], f[7]);
  }
  xx[i] = s;
  xxf[i] = (float)s;
}

// ---------------------------------------------------------------------------
// k_pq (Path B fallback): P/Q GEMMs only.
// ---------------------------------------------------------------------------
__global__ __launch_bounds__(256) void k_pq(const float* __restrict__ x,
                                            const float* __restrict__ W,
                                            float* __restrict__ P,
                                            float* __restrict__ Q) {
  __shared__ float tile[64][OO + 1];
  const int t = threadIdx.x;
  const int jj = t & 63, og = t >> 6;
  const int pt0 = blockIdx.x * 64;
  const int b = pt0 >> 11;
  const int jn = (pt0 & (NN - 1)) + jj;

  float xcol[CC];
#pragma unroll
  for (int c = 0; c < CC; ++c) xcol[c] = x[((size_t)(b * CC + c) << 11) + jn];

  for (int oo = 0; oo < 32; ++oo) {
    int o = og * 32 + oo;
    const float* wr = W + (size_t)o * (2 * CC);
    float sp = 0.f;
#pragma unroll
    for (int c = 0; c < CC; ++c) sp = fmaf(wr[c], xcol[c], sp);
    tile[jj][o] = sp;
  }
  __syncthreads();
  for (int it = 0; it < 32; ++it) {
    int r = it * 2 + (t >> 7);
    P[((size_t)(pt0 + r)) * OO + (t & 127)] = tile[r][t & 127];
  }
  __syncthreads();
  for (int oo = 0; oo < 32; ++oo) {
    int o = og * 32 + oo;
    const float* wr = W + (size_t)o * (2 * CC);
    float sq = 0.f;
#pragma unroll
    for (int c = 0; c < CC; ++c) sq = fmaf(wr[CC + c] - wr[c], xcol[c], sq);
    tile[jj][o] = sq;
  }
  __syncthreads();
  for (int it = 0; it < 32; ++it) {
    int r = it * 2 + (t >> 7);
    Q[((size_t)(pt0 + r)) * OO + (t & 127)] = tile[r][t & 127];
  }
}

// ---------------------------------------------------------------------------
// k_knn (R18 — best measured: 75.2us, no spills, no conflicts): 32-row tiles,
// 512 blocks x 1024 thr; phase A/B split in two halves (32 AGPRs live);
// phase C dual-row interleaved (b128 keys, reg masks, CANDT 28); phase D
// fused gather-stats. R19's 16-row/8-waves variant spilled 68MB (VGPR=32 cap).
// ---------------------------------------------------------------------------
__device__ __forceinline__ void exact_radix_q(const uint4* kq, int lane,
                                              unsigned& tau, unsigned& mask,
                                              int& myc, int& pre, int& tot) {
  tau = 0;
  for (int bit = 15; bit >= 0; --bit) {
    unsigned cnd = tau | (1u << bit);
    int cc = 0;
#pragma unroll
    for (int g = 0; g < 4; ++g) {
      const unsigned wds[4] = {kq[g].x, kq[g].y, kq[g].z, kq[g].w};
#pragma unroll
      for (int e = 0; e < 4; ++e) {
        cc += ((wds[e] & 0xffffu) >= cnd) ? 1 : 0;
        cc += ((wds[e] >> 16) >= cnd) ? 1 : 0;
      }
    }
#pragma unroll
    for (int off = 1; off < 64; off <<= 1) cc += __shfl_xor(cc, off, 64);
    if (cc >= CANDT) tau = cnd;
  }
  mask = 0;
#pragma unroll
  for (int g = 0; g < 4; ++g) {
    const unsigned wds[4] = {kq[g].x, kq[g].y, kq[g].z, kq[g].w};
#pragma unroll
    for (int e = 0; e < 4; ++e) {
      mask |= ((wds[e] & 0xffffu) >= tau ? 1u : 0u) << (g * 8 + e * 2);
      mask |= ((wds[e] >> 16) >= tau ? 1u : 0u) << (g * 8 + e * 2 + 1);
    }
  }
  myc = __popc(mask); pre = myc;
#pragma unroll
  for (int off = 1; off < 64; off <<= 1) {
    int o = __shfl_up(pre, off, 64);
    pre += (lane >= off) ? o : 0;
  }
  tot = __shfl(pre, 63, 64);
}

__global__ __launch_bounds__(1024, 4) void k_knn(
    const ushort* __restrict__ xT, const float* __restrict__ xxf,
    const float* __restrict__ xTf, const double* __restrict__ xx,
    int* __restrict__ idx, const float* __restrict__ P,
    const float* __restrict__ Q, float* __restrict__ partial,
    float* __restrict__ vmaxA, float* __restrict__ vminA) {
  extern __shared__ char smem[];
  ushort (*Sb)[NN] = (ushort(*)[NN])smem;          // [32][2048] u16 keys 128KB
  int (*CjS)[64] = (int(*)[64])(smem + 32 * NN * 2);           // [32][64] 8KB
  double (*SdS)[64] = (double(*)[64])(smem + 32 * NN * 2 + 8192); // [32][64] 16KB
  float* redF = (float*)SdS;                       // reuse as [2][8][128] in D
  int (*sIdxL)[KK] = (int(*)[KK])(smem + 32 * NN * 2 + 8192 + 16384); // 2.5KB
  const int t = threadIdx.x;
  const int w = t >> 6, lane = t & 63;
  const int bidswz = ((blockIdx.x & 7) << 6) + (blockIdx.x >> 3); // batch/XCD
  const int b = bidswz >> 6;
  const int i0 = (bidswz & 63) << 5;
  const int lr = lane & 31, lh = lane >> 5;
  const ushort* xTb = xT + (((size_t)b) << 11) * CC;
  const float* xxfb = xxf + (b << 11);

  // ---- Phase A+B in 2 halves: only 32 AGPRs (acc2[2]) live at a time ----
  const ushort* Ap = xTb + (size_t)(i0 + lr) * CC + lh * 8;
  bf8v a0 = *(const bf8v*)(Ap);
  bf8v a1 = *(const bf8v*)(Ap + 16);
  bf8v a2 = *(const bf8v*)(Ap + 32);
  bf8v a3 = *(const bf8v*)(Ap + 48);
  const int j0w = w << 7;
#pragma unroll 1
  for (int h = 0; h < 2; ++h) {
    f32x16 acc2[2];
#pragma unroll
    for (int u = 0; u < 2; ++u)
#pragma unroll
      for (int q = 0; q < 16; ++q) acc2[u][q] = 0.f;
#pragma unroll
    for (int u = 0; u < 2; ++u) {
      const int tt = h * 2 + u;
      const ushort* Bp = xTb + (size_t)(j0w + tt * 32 + lr) * CC + lh * 8;
      bf8v b0 = *(const bf8v*)(Bp);
      bf8v b1 = *(const bf8v*)(Bp + 16);
      bf8v b2 = *(const bf8v*)(Bp + 32);
      bf8v b3 = *(const bf8v*)(Bp + 48);
      acc2[u] = __builtin_amdgcn_mfma_f32_32x32x16_bf16(a0, b0, acc2[u], 0, 0, 0);
      acc2[u] = __builtin_amdgcn_mfma_f32_32x32x16_bf16(a1, b1, acc2[u], 0, 0, 0);
      acc2[u] = __builtin_amdgcn_mfma_f32_32x32x16_bf16(a2, b2, acc2[u], 0, 0, 0);
      acc2[u] = __builtin_amdgcn_mfma_f32_32x32x16_bf16(a3, b3, acc2[u], 0, 0, 0);
    }
#pragma unroll
    for (int u = 0; u < 2; ++u) {
      const int tt = h * 2 + u;
      int j = j0w + tt * 32 + lr;
      float xv = xxfb[j];
#pragma unroll
      for (int q = 0; q < 16; ++q) {
        int rr = (q & 3) + 8 * (q >> 2) + 4 * lh;  // 32x32 C/D map (m74/m101)
        float sv = fmaf(2.f, acc2[u][q], -xv);
        unsigned uu = __float_as_uint(sv);
        uu ^= (0x80000000u | (unsigned)((int)uu >> 31)); // monotone u32
        Sb[rr][j] = (ushort)(uu >> 16);
      }
    }
  }
  __syncthreads();

  // ---- Phase C: rows rrA=w, rrB=w+16 fully interleaved (b128 key reads) ----
  const float* xTfb = xTf + (((size_t)b) << 11) * CC;
  const double* xxb = xx + (b << 11);
  const int rrA = w, rrB = w + 16;
  const int irowA = i0 + rrA, irowB = i0 + rrB;

  uint4 kqA[4], kqB[4];
  unsigned tA0 = 0, tA1 = 0, tA2 = 0, tA3 = 0;
  unsigned tB0 = 0, tB1 = 0, tB2 = 0, tB3 = 0;
#pragma unroll
  for (int g = 0; g < 4; ++g) {
    uint4 rawA = *(const uint4*)(&Sb[rrA][lane * 8 + g * 512]);
    uint4 rawB = *(const uint4*)(&Sb[rrB][lane * 8 + g * 512]);
    kqA[g] = rawA; kqB[g] = rawB;
    const unsigned wA[4] = {rawA.x, rawA.y, rawA.z, rawA.w};
    const unsigned wB[4] = {rawB.x, rawB.y, rawB.z, rawB.w};
#pragma unroll
    for (int e = 0; e < 4; ++e) {
      unsigned kA0 = wA[e] & 0xffffu, kA1 = wA[e] >> 16;
      unsigned kB0 = wB[e] & 0xffffu, kB1 = wB[e] >> 16;
      unsigned mx, mn;
      mx = kA0 > tA0 ? kA0 : tA0; mn = kA0 > tA0 ? tA0 : kA0; tA0 = mx;
      mx = mn > tA1 ? mn : tA1; mn = mn > tA1 ? tA1 : mn; tA1 = mx;
      mx = mn > tA2 ? mn : tA2; mn = mn > tA2 ? tA2 : mn; tA2 = mx;
      tA3 = mn > tA3 ? mn : tA3;
      mx = kB0 > tB0 ? kB0 : tB0; mn = kB0 > tB0 ? tB0 : kB0; tB0 = mx;
      mx = mn > tB1 ? mn : tB1; mn = mn > tB1 ? tB1 : mn; tB1 = mx;
      mx = mn > tB2 ? mn : tB2; mn = mn > tB2 ? tB2 : mn; tB2 = mx;
      tB3 = mn > tB3 ? mn : tB3;
      mx = kA1 > tA0 ? kA1 : tA0; mn = kA1 > tA0 ? tA0 : kA1; tA0 = mx;
      mx = mn > tA1 ? mn : tA1; mn = mn > tA1 ? tA1 : mn; tA1 = mx;
      mx = mn > tA2 ? mn : tA2; mn = mn > tA2 ? tA2 : mn; tA2 = mx;
      tA3 = mn > tA3 ? mn : tA3;
      mx = kB1 > tB0 ? kB1 : tB0; mn = kB1 > tB0 ? tB0 : kB1; tB0 = mx;
      mx = mn > tB1 ? mn : tB1; mn = mn > tB1 ? tB1 : mn; tB1 = mx;
      mx = mn > tB2 ? mn : tB2; mn = mn > tB2 ? tB2 : mn; tB2 = mx;
      tB3 = mn > tB3 ? mn : tB3;
    }
  }
  // dual MSB radix with capped (top-4) ballot counts
  unsigned tauA = 0, tauB = 0;
  for (int bit = 15; bit >= 0; --bit) {
    unsigned cA = tauA | (1u << bit), cB = tauB | (1u << bit);
    int totA_ = __popcll(__ballot(tA0 >= cA)) + __popcll(__ballot(tA1 >= cA)) +
                __popcll(__ballot(tA2 >= cA)) + __popcll(__ballot(tA3 >= cA));
    int totB_ = __popcll(__ballot(tB0 >= cB)) + __popcll(__ballot(tB1 >= cB)) +
                __popcll(__ballot(tB2 >= cB)) + __popcll(__ballot(tB3 >= cB));
    if (totA_ >= CANDT) tauA = cA;
    if (totB_ >= CANDT) tauB = cB;
  }
  // dual masks + dual prefix scan
  unsigned maskA = 0, maskB = 0;
#pragma unroll
  for (int g = 0; g < 4; ++g) {
    const unsigned wA[4] = {kqA[g].x, kqA[g].y, kqA[g].z, kqA[g].w};
    const unsigned wB[4] = {kqB[g].x, kqB[g].y, kqB[g].z, kqB[g].w};
#pragma unroll
    for (int e = 0; e < 4; ++e) {
      maskA |= ((wA[e] & 0xffffu) >= tauA ? 1u : 0u) << (g * 8 + e * 2);
      maskA |= ((wA[e] >> 16) >= tauA ? 1u : 0u) << (g * 8 + e * 2 + 1);
      maskB |= ((wB[e] & 0xffffu) >= tauB ? 1u : 0u) << (g * 8 + e * 2);
      maskB |= ((wB[e] >> 16) >= tauB ? 1u : 0u) << (g * 8 + e * 2 + 1);
    }
  }
  int mycA = __popc(maskA), mycB = __popc(maskB);
  int preA = mycA, preB = mycB;
#pragma unroll
  for (int off = 1; off < 64; off <<= 1) {
    int oA = __shfl_up(preA, off, 64);
    int oB = __shfl_up(preB, off, 64);
    preA += (lane >= off) ? oA : 0;
    preB += (lane >= off) ? oB : 0;
  }
  int totA = __shfl(preA, 63, 64);
  int totB = __shfl(preB, 63, 64);
  if (totA > 64) exact_radix_q(kqA, lane, tauA, maskA, mycA, preA, totA); // cold
  if (totB > 64) exact_radix_q(kqB, lane, tauB, maskB, mycB, preB, totB); // cold
  {
    int slot = preA - mycA;
    unsigned m2 = maskA;
    while (m2) {
      int bp = __builtin_ctz(m2); m2 &= m2 - 1;
      if (slot < 64) CjS[rrA][slot] = lane * 8 + ((bp >> 3) << 9) + (bp & 7);
      ++slot;
    }
  }
  {
    int slot = preB - mycB;
    unsigned m2 = maskB;
    while (m2) {
      int bp = __builtin_ctz(m2); m2 &= m2 - 1;
      if (slot < 64) CjS[rrB][slot] = lane * 8 + ((bp >> 3) << 9) + (bp & 7);
      ++slot;
    }
  }
  const int cntA = totA > 64 ? 64 : totA;
  const int cntB = totB > 64 ? 64 : totB;

  // dual fp64 rescore (accumulation order identical to R3..R18)
  int jA = CjS[rrA][lane < cntA ? lane : 0];
  int jB = CjS[rrB][lane < cntB ? lane : 0];
  const float* xiA = xTfb + (size_t)irowA * CC;
  const float* xiB = xTfb + (size_t)irowB * CC;
  const float* xjA = xTfb + (size_t)jA * CC;
  const float* xjB = xTfb + (size_t)jB * CC;
  double dA0 = 0, dA1 = 0, dA2 = 0, dA3 = 0;
  double dB0 = 0, dB1 = 0, dB2 = 0, dB3 = 0;
#pragma unroll
  for (int c = 0; c < CC; c += 4) {
    float4 fiA = *(const float4*)(xiA + c);
    float4 fjA = *(const float4*)(xjA + c);
    float4 fiB = *(const float4*)(xiB + c);
    float4 fjB = *(const float4*)(xjB + c);
    dA0 = fma((double)fiA.x, (double)fjA.x, dA0);
    dB0 = fma((double)fiB.x, (double)fjB.x, dB0);
    dA1 = fma((double)fiA.y, (double)fjA.y, dA1);
    dB1 = fma((double)fiB.y, (double)fjB.y, dB1);
    dA2 = fma((double)fiA.z, (double)fjA.z, dA2);
    dB2 = fma((double)fiB.z, (double)fjB.z, dB2);
    dA3 = fma((double)fiA.w, (double)fjA.w, dA3);
    dB3 = fma((double)fiB.w, (double)fjB.w, dB3);
  }
  double scA = 2.0 * ((dA0 + dA1) + (dA2 + dA3)) - xxb[jA];
  double scB = 2.0 * ((dB0 + dB1) + (dB2 + dB3)) - xxb[jB];

  // dual rank via LDS broadcast reads (same-wave write->read)
  SdS[rrA][lane] = scA;
  SdS[rrB][lane] = scB;
  int rankA = 0, rankB = 0;
  const int cmax = cntA > cntB ? cntA : cntB;
  for (int mm = 0; mm < cmax; ++mm) {
    int mA = mm < cntA ? mm : 0;
    int mB = mm < cntB ? mm : 0;
    double smA = SdS[rrA][mA]; int jmA = CjS[rrA][mA];
    double smB = SdS[rrB][mB]; int jmB = CjS[rrB][mB];
    if (mm < cntA) rankA += (smA > scA || (smA == scA && jmA < jA)) ? 1 : 0;
    if (mm < cntB) rankB += (smB > scB || (smB == scB && jmB < jB)) ? 1 : 0;
  }
  if (lane < cntA && rankA < KK) {
    idx[(size_t)((b << 11) + irowA) * KK + rankA] = jA;
    sIdxL[rrA][rankA] = jA;
  }
  if (lane < cntB && rankB < KK) {
    idx[(size_t)((b << 11) + irowB) * KK + rankB] = jB;
    sIdxL[rrB][rankB] = jB;
  }

  // ---- Phase D: fused gather-stats (skipped when P==nullptr, Path B) ----
  if (P != nullptr) {
    __syncthreads();                               // sIdxL complete; SdS free
    const int grp = t >> 7;                        // 0..7 (4 points each)
    const int o = t & 127;
    float s = 0.f, s2 = 0.f;
#pragma unroll
    for (int pp = 0; pp < 4; ++pp) {
      const int pl = grp * 4 + pp;                 // local row 0..31
      const int pt = (b << 11) + i0 + pl;          // global point
      float qv = Q[(size_t)pt * OO + o];
      float vmax = -3.0e38f, vmin = 3.0e38f;
#pragma unroll
      for (int k = 0; k < KK; ++k) {
        float v = P[((size_t)((b << 11) + sIdxL[pl][k])) * OO + o] + qv;
        s += v;
        s2 = fmaf(v, v, s2);
        vmax = fmaxf(vmax, v);
        vmin = fminf(vmin, v);
      }
      vmaxA[(size_t)pt * OO + o] = vmax;
      vminA[(size_t)pt * OO + o] = vmin;
    }
    redF[grp * 128 + o] = s;
    redF[1024 + grp * 128 + o] = s2;
    __syncthreads();
    if (t < 128) {
      float as = 0.f, as2 = 0.f;
#pragma unroll
      for (int g = 0; g < 8; ++g) {                // fixed order: deterministic
        as  += redF[g * 128 + t];
        as2 += redF[1024 + g * 128 + t];
      }
      partial[(size_t)bidswz * 128 + t]               = as;
      partial[(size_t)NPART * 128 + (size_t)bidswz * 128 + t] = as2;
    }
  }
}

// ---------------------------------------------------------------------------
// k_stats (Path B fallback): standalone gather-stats.
// ---------------------------------------------------------------------------
__global__ __launch_bounds__(256) void k_stats(const float* __restrict__ P,
                                               const float* __restrict__ Q,
                                               const int* __restrict__ idx,
                                               float* __restrict__ partial) {
  __shared__ int sIdx[16 * KK];
  __shared__ float red[512];
  const int t = threadIdx.x;
  const int o = t & 127, half = t >> 7;
  const int bid = (blockIdx.x & 7) * 128 + (blockIdx.x >> 3);
  const int pt0 = bid * 16;
  const int b = pt0 >> 11;
  if (t < 160)
    *(int2*)(sIdx + t * 2) = *(const int2*)(idx + (size_t)pt0 * KK + t * 2);
  __syncthreads();

  float s = 0.f, s2 = 0.f;
  for (int it = 0; it < 8; ++it) {
    int pl = it * 2 + half;
    int pt = pt0 + pl;
    float qv = Q[(size_t)pt * OO + o];
    const int* ip = sIdx + pl * KK;
#pragma unroll
    for (int k = 0; k < KK; ++k) {
      float v = P[((size_t)((b << 11) + ip[k])) * OO + o] + qv;
      s += v;
      s2 = fmaf(v, v, s2);
    }
  }
  red[t] = s; red[256 + t] = s2;
  __syncthreads();
  if (t < 128) {
    partial[bid * 128 + o]                = red[t] + red[t + 128];
    partial[NPARTB * 128 + bid * 128 + o] = red[256 + t] + red[256 + t + 128];
  }
}

// ---------------------------------------------------------------------------
// k_fin: single-kernel BN finalize. 128 blocks (one per o); npart variable.
// ---------------------------------------------------------------------------
__global__ __launch_bounds__(256) void k_fin(const float* __restrict__ partial,
                                             const float* __restrict__ gamma,
                                             const float* __restrict__ beta,
                                             float* __restrict__ ss, int npart) {
  __shared__ float red[2][256];
  const int o = blockIdx.x;
  const int t = threadIdx.x;
  float s = 0.f, s2 = 0.f;
  for (int blk = t; blk < npart; blk += 256) {
    s  += partial[(size_t)blk * 128 + o];
    s2 += partial[(size_t)npart * 128 + (size_t)blk * 128 + o];
  }
  red[0][t] = s; red[1][t] = s2;
  __syncthreads();
  for (int st = 128; st >= 1; st >>= 1) {
    if (t < st) { red[0][t] += red[0][t + st]; red[1][t] += red[1][t + st]; }
    __syncthreads();
  }
  if (t == 0) {
    float mean = red[0][0] * (1.0f / M_TOT);
    float var  = red[1][0] * (1.0f / M_TOT) - mean * mean;
    float rs = 1.0f / sqrtf(var + 1e-5f);
    float scale = gamma[o] * rs;
    ss[o] = scale;
    ss[128 + o] = beta[o] - mean * scale;
  }
}

// ---------------------------------------------------------------------------
// k_out: BN affine -> exact GELU -> max over k -> out[b][o][n].
// ---------------------------------------------------------------------------
__global__ __launch_bounds__(256, 8) void k_out(const float* __restrict__ P,
                                                const float* __restrict__ Q,
                                                const int* __restrict__ idx,
                                                const float* __restrict__ ss,
                                                const float* __restrict__ vmaxA,
                                                const float* __restrict__ vminA,
                                                int use_minmax,
                                                float* __restrict__ out) {
  __shared__ float tile[32][OO + 1];               // 16.5 KB
  const int t = threadIdx.x;
  const int o = t & 127, half = t >> 7;
  const int bid = (blockIdx.x & 7) * 64 + (blockIdx.x >> 3);   // batch/XCD
  const float scale = ss[o], shift = ss[128 + o];
  const int pt0 = bid * 32;
  const int b = pt0 >> 11;
  const float inv_sqrt2 = 0.70710678118654752f;
  for (int it = 0; it < 16; ++it) {
    int pl = it * 2 + half;
    int pt = pt0 + pl;
    float vmax, vmin;
    if (use_minmax) {
      vmax = vmaxA[(size_t)pt * OO + o];
      vmin = vminA[(size_t)pt * OO + o];
    } else {
      float qv = Q[(size_t)pt * OO + o];
      const int* ip = idx + (size_t)pt * KK;
      vmax = -3.0e38f; vmin = 3.0e38f;
#pragma unroll
      for (int k = 0; k < KK; ++k) {
        float v = P[((size_t)((b << 11) + ip[k])) * OO + o] + qv;
        vmax = fmaxf(vmax, v);
        vmin = fminf(vmin, v);
      }
    }
    float ymax, ymin;
    if (scale >= 0.f) { ymax = fmaf(vmax, scale, shift); ymin = fmaf(vmin, scale, shift); }
    else              { ymax = fmaf(vmin, scale, shift); ymin = fmaf(vmax, scale, shift); }
    float g;
    if (ymax > 0.f) {
      g = 0.5f * ymax * (1.0f + erff(ymax * inv_sqrt2));
    } else {
      float g1 = 0.5f * ymax * (1.0f + erff(ymax * inv_sqrt2));
      float g2 = 0.5f * ymin * (1.0f + erff(ymin * inv_sqrt2));
      g = fmaxf(g1, g2);
    }
    tile[pl][o] = g;
  }
  __syncthreads();
  const int n0 = pt0 & (NN - 1);
  for (int rep = 0; rep < 16; ++rep) {
    int oo = rep * 8 + (t >> 5);
    int nn = t & 31;
    out[((size_t)(b * OO + oo) << 11) + n0 + nn] = tile[nn][oo];
  }
}

// ---------------------------------------------------------------------------
extern "C" void kernel_launch(void* const* d_in, const int* in_sizes, int n_in,
                              void* d_out, int out_size, void* d_ws, size_t ws_size,
                              hipStream_t stream) {
  const float* x     = (const float*)d_in[0];
  const float* W     = (const float*)d_in[1];
  const float* gamma = (const float*)d_in[2];
  const float* beta  = (const float*)d_in[3];
  float* out = (float*)d_out;

  const int knn_lds = 32 * NN * 2 + 8192 + 16384 + 32 * KK * 4;  // 158208 B
  hipFuncSetAttribute((const void*)k_knn,
                      hipFuncAttributeMaxDynamicSharedMemorySize, knn_lds);

  const size_t needA = 131072 + 65536 + 1310720 + (size_t)2 * NPARTB * 128 * 4 +
                       1024 + 4ull * 8388608;

  if (ws_size >= needA) {
    // Path A layout
    double* xx   = (double*)d_ws;                      // 131072 B
    float*  xxf  = (float*)(xx + BB * NN);             // 65536 B
    int*    idxp = (int*)(xxf + BB * NN);              // 1310720 B
    float*  part = (float*)(idxp + (size_t)BB * NN * KK); // 1 MB
    float*  ss   = part + 2 * NPARTB * 128;            // 1024 B
    float*  P    = ss + 256;                           // 8 MB
    float*  Q    = P + (size_t)BB * NN * OO;           // 8 MB
    ushort* xT   = (ushort*)(Q + (size_t)BB * NN * OO);// 2 MB
    float*  xTf  = (float*)(xT + (size_t)BB * NN * CC);// 4 MB
    float*  vmax = xTf + (size_t)BB * NN * CC;         // 8 MB (no alias: knn-D)
    float*  vmin = vmax + (size_t)BB * NN * OO;        // 8 MB
    const size_t needSafe = (size_t)((char*)(vmin + (size_t)BB * NN * OO) - (char*)d_ws);
    if (ws_size >= needSafe) {
      hipLaunchKernelGGL(k_pqprep, dim3(BB * NN / 32), dim3(256), 0, stream,
                         x, W, P, Q, xT, xTf, xx, xxf);
      hipLaunchKernelGGL(k_knn, dim3(BB * NN / 32), dim3(1024), knn_lds, stream,
                         xT, xxf, xTf, xx, idxp, P, Q, part, vmax, vmin);
      hipLaunchKernelGGL(k_fin, dim3(128), dim3(256), 0, stream, part, gamma, beta, ss, NPART);
      hipLaunchKernelGGL(k_out, dim3(BB * NN / 32), dim3(256), 0, stream,
                         P, Q, idxp, ss, vmax, vmin, 1, out);
      return;
    }
    // ws too small for safe vmax/vmin: alias xT/xTf region, no fused stats
    ushort* xTa  = (ushort*)(Q + (size_t)BB * NN * OO);
    float*  xTfa = (float*)(xTa + (size_t)BB * NN * CC);
    hipLaunchKernelGGL(k_pqprep, dim3(BB * NN / 32), dim3(256), 0, stream,
                       x, W, P, Q, xTa, xTfa, xx, xxf);
    hipLaunchKernelGGL(k_knn, dim3(BB * NN / 32), dim3(1024), knn_lds, stream,
                       xTa, xxf, xTfa, xx, idxp,
                       (const float*)nullptr, (const float*)nullptr,
                       (float*)nullptr, (float*)nullptr, (float*)nullptr);
    hipLaunchKernelGGL(k_stats, dim3(NPARTB), dim3(256), 0, stream,
                       P, Q, idxp, part);
    hipLaunchKernelGGL(k_fin, dim3(128), dim3(256), 0, stream, part, gamma, beta, ss, NPARTB);
    hipLaunchKernelGGL(k_out, dim3(BB * NN / 32), dim3(256), 0, stream,
                       P, Q, idxp, ss, (const float*)nullptr, (const float*)nullptr, 0, out);
  } else {
    // Path B layout (minimal ws)
    double* xx   = (double*)d_ws;
    int*    idxp = (int*)(xx + BB * NN);
    float*  P    = (float*)(idxp + (size_t)BB * NN * KK);
    float*  Q    = P + (size_t)BB * NN * OO;
    float*  part = Q + (size_t)BB * NN * OO;
    float*  ss   = part + 2 * NPARTB * 128;
    ushort* xT   = (ushort*)P;
    float*  xTf  = P + (size_t)BB * NN * (CC / 2);
    float*  xxf  = Q;

    hipLaunchKernelGGL(k_prep, dim3(BB * NN / 256), dim3(256), 0, stream,
                       x, xT, xTf, xx, xxf);
    hipLaunchKernelGGL(k_knn, dim3(BB * NN / 32), dim3(1024), knn_lds, stream,
                       xT, xxf, xTf, xx, idxp,
                       (const float*)nullptr, (const float*)nullptr,
                       (float*)nullptr, (float*)nullptr, (float*)nullptr);
    hipLaunchKernelGGL(k_pq, dim3(BB * NN / 64), dim3(256), 0, stream, x, W, P, Q);
    hipLaunchKernelGGL(k_stats, dim3(NPARTB), dim3(256), 0, stream,
                       P, Q, idxp, part);
    hipLaunchKernelGGL(k_fin, dim3(128), dim3(256), 0, stream, part, gamma, beta, ss, NPARTB);
    hipLaunchKernelGGL(k_out, dim3(BB * NN / 32), dim3(256), 0, stream,
                       P, Q, idxp, ss, (const float*)nullptr, (const float*)nullptr, 0, out);
  }
}